// Round 3
// baseline (289.033 us; speedup 1.0000x reference)
//
#include <hip/hip_runtime.h>

#define HW    512
#define OUTW  128
#define NIMG  96                          // 32*3
#define N_HR  ((long long)NIMG*HW*HW)     // 25165824
#define N_LR  ((long long)NIMG*OUTW*OUTW) // 1572864
#define NPART (NIMG*32)                   // one slot per wave (4 out rows each)

// PyTorch bicubic kernel, a = -0.75
__device__ __forceinline__ float cubic075(float x){
    float ax = fabsf(x);
    float ax2 = ax*ax, ax3 = ax2*ax;
    const float A = -0.75f;
    float f1 = (A+2.f)*ax3 - (A+3.f)*ax2 + 1.f;
    float f2 = A*ax3 - 5.f*A*ax2 + 8.f*A*ax - 4.f*A;
    return ax <= 1.f ? f1 : (ax < 2.f ? f2 : 0.f);
}

// scale=4 antialiased window: 16 taps, dist=(k-7.5)/4, normalized.
// Shift-invariant across all output positions (verified absmax=0.0).
__device__ __forceinline__ void get_weights(float w[16]){
    float s = 0.f;
#pragma unroll
    for (int k = 0; k < 16; ++k){
        float d = ((float)k - 7.5f) * 0.25f;
        w[k] = cubic075(d);
        s += w[k];
    }
#pragma unroll
    for (int k = 0; k < 16; ++k) w[k] /= s;
}

// R3: branch-free unrolled phases (so the waitcnt pass can COUNT outstanding
// loads and emit vmcnt(N>0) at each consume) + an asm memory-clobber pin
// after each issue group (so the scheduler cannot SINK the unguarded loads
// next to their consumers -- that was R1's failure: VGPR 76->36, pipeline
// collapsed). Loads write registers, so the pin constrains placement only,
// not waiting. Issue-before-consume ordering gives each pred row 4 full
// iterations of in-flight time. Geometry = R0 (4 out rows/wave, 768 blocks,
// lowest halo traffic): occupancy is VGPR-capped at 4 waves/SIMD anyway
// (R2 lesson), so ILP -- not TLP -- must cover latency.
#define PIN() asm volatile("" ::: "memory")

__global__ __launch_bounds__(256) void kmain(const float* __restrict__ pred,
                                             const float* __restrict__ tgt,
                                             const float* __restrict__ lr,
                                             double* __restrict__ part){
    const int img = blockIdx.x >> 3;
    const int tid = threadIdx.x;
    const int w   = tid >> 6;                 // wave in block 0..3
    const int l   = tid & 63;
    const int gw  = ((blockIdx.x & 7) << 2) + w;  // wave in image 0..31
    const int o0  = gw << 2;                  // first output row
    const int s   = (gw << 4) - 6;            // first (unclamped) input row
    const int li  = 2*l;

    float wt[16]; get_weights(wt);
    const float* P = pred + (size_t)img * (HW*HW);
    const float* T = tgt  + (size_t)img * (HW*HW);
    const float* L = lr   + (size_t)img * (OUTW*OUTW);

    float acc[4][2] = {{0.f,0.f},{0.f,0.f},{0.f,0.f},{0.f,0.f}};
    float pix_acc = 0.f, lr_acc = 0.f;

    float4 p[4][2];   // pred ring buffer, prefetch distance 4
    float4 t[4][2];   // tgt ring buffer (rows 6..21 only)

#define PREDROW(i) ((const float4*)(P + (size_t)min(HW-1, max(0, s+(i)))*HW))
#define TGTROW(i)  ((const float4*)(T + (size_t)(s+(i))*HW))
#define ISSUE_P(i) do{ const float4* _rp = PREDROW(i); \
                       p[(i)&3][0]=_rp[li]; p[(i)&3][1]=_rp[li+1]; }while(0)
#define ISSUE_T(i) do{ const float4* _tp = TGTROW(i); \
                       t[(i)&3][0]=_tp[li]; t[(i)&3][1]=_tp[li+1]; }while(0)

#define CONSUME(i, DOPIX) do{                                                   \
    const float4 c0 = p[(i)&3][0], c1 = p[(i)&3][1];                            \
    const float p0=c0.x,p1v=c0.y,p2v=c0.z,p3=c0.w,                              \
                p4=c1.x,p5=c1.y,p6=c1.z,p7=c1.w;                                \
    if (DOPIX){                                                                 \
        const float4 t0 = t[(i)&3][0], t1 = t[(i)&3][1];                        \
        pix_acc += fabsf(p0-t0.x)+fabsf(p1v-t0.y)+fabsf(p2v-t0.z)+fabsf(p3-t0.w)\
                 + fabsf(p4-t1.x)+fabsf(p5-t1.y)+fabsf(p6-t1.z)+fabsf(p7-t1.w); \
    }                                                                           \
    float Lm6 = __shfl_up(p2v,1,64), Lm5 = __shfl_up(p3,1,64),                  \
          Lm4 = __shfl_up(p4,1,64),  Lm3 = __shfl_up(p5,1,64),                  \
          Lm2 = __shfl_up(p6,1,64),  Lm1 = __shfl_up(p7,1,64);                  \
    float R8  = __shfl_down(p0,1,64), R9  = __shfl_down(p1v,1,64),              \
          R10 = __shfl_down(p2v,1,64),R11 = __shfl_down(p3,1,64),               \
          R12 = __shfl_down(p4,1,64), R13 = __shfl_down(p5,1,64);               \
    if (l == 0){ Lm6=p0; Lm5=p0; Lm4=p0; Lm3=p0; Lm2=p0; Lm1=p0; }              \
    if (l == 63){ R8=p7; R9=p7; R10=p7; R11=p7; R12=p7; R13=p7; }               \
    float w20[20] = {Lm6,Lm5,Lm4,Lm3,Lm2,Lm1,p0,p1v,p2v,p3,p4,p5,p6,p7,         \
                     R8,R9,R10,R11,R12,R13};                                    \
    float h0 = 0.f, h1 = 0.f;                                                   \
    _Pragma("unroll")                                                           \
    for (int k = 0; k < 16; ++k){ h0 += wt[k]*w20[k]; h1 += wt[k]*w20[k+4]; }   \
    _Pragma("unroll")                                                           \
    for (int q = 0; q < 4; ++q){                                                \
        int kk = (i) - 4*q;                                                     \
        if (kk >= 0 && kk < 16){ acc[q][0] += wt[kk]*h0; acc[q][1] += wt[kk]*h1; } \
    }                                                                           \
}while(0)

    // prime the pred pipeline: rows 0..3 in flight
    ISSUE_P(0); ISSUE_P(1); ISSUE_P(2); ISSUE_P(3); PIN();

#pragma unroll
    for (int i = 0; i < 6; ++i){          // prolog: bottom halo rows
        ISSUE_P(i+4);                     // rows 4..9 (clamped)
        if (i+4 >= 6) ISSUE_T(i+4);       // folds per unrolled body
        PIN();
        CONSUME(i, false);
    }
#pragma unroll
    for (int i = 6; i < 22; ++i){         // steady state: pix + resize
        if (i+4 < 26) ISSUE_P(i+4);       // rows 10..25 (clamp handles top)
        if (i+4 < 22) ISSUE_T(i+4);       // folds per unrolled body
        PIN();
        CONSUME(i, true);                 // rows s+6..s+21 always in-bounds
    }
#pragma unroll
    for (int i = 22; i < 28; ++i){        // epilog: top halo rows
        if (i+4 < 28) ISSUE_P(i+4);       // rows 26,27 only; folds
        PIN();
        CONSUME(i, false);
    }

#undef CONSUME
#undef ISSUE_T
#undef ISSUE_P
#undef TGTROW
#undef PREDROW

    // lr term: lane l holds out cols 2l,2l+1 for rows o0..o0+3
#pragma unroll
    for (int q = 0; q < 4; ++q){
        const float2 lv = *(const float2*)(L + (size_t)(o0+q)*OUTW + li);
        lr_acc += fabsf(acc[q][0]-lv.x) + fabsf(acc[q][1]-lv.y);
    }

    // intra-wave reduction, one slot per wave (no atomics, no init needed)
#pragma unroll
    for (int off = 32; off > 0; off >>= 1){
        pix_acc += __shfl_down(pix_acc, off, 64);
        lr_acc  += __shfl_down(lr_acc,  off, 64);
    }
    if (l == 0){
        const int slot = (blockIdx.x << 2) + w;
        part[slot]         = (double)pix_acc;
        part[NPART + slot] = (double)lr_acc;
    }
}

__global__ __launch_bounds__(256) void k3(const double* __restrict__ part,
                                          float* __restrict__ out){
    const int t = threadIdx.x;
    double v1 = 0.0, v2 = 0.0;
    for (int i = t; i < NPART; i += 256){
        v1 += part[i];
        v2 += part[NPART + i];
    }
#pragma unroll
    for (int off = 32; off > 0; off >>= 1){
        v1 += __shfl_down(v1, off, 64);
        v2 += __shfl_down(v2, off, 64);
    }
    __shared__ double s1[4], s2[4];
    const int lane = t & 63, wid = t >> 6;
    if (lane == 0){ s1[wid] = v1; s2[wid] = v2; }
    __syncthreads();
    if (t == 0){
        double S1 = s1[0]+s1[1]+s1[2]+s1[3];
        double S2 = s2[0]+s2[1]+s2[2]+s2[3];
        float pix     = (float)(S1 / (double)N_HR);
        float lr_term = (float)(S2 / (double)N_LR);
        float pair    = 0.f;
        float consist = 1.0f * lr_term + 1.0f * pair;   // LAM_LR, LAM_PAIR
        float total   = pix + 0.1f * consist;           // LAM_CONSIST
        out[0] = total; out[1] = pix; out[2] = consist; out[3] = lr_term; out[4] = pair;
    }
}

extern "C" void kernel_launch(void* const* d_in, const int* in_sizes, int n_in,
                              void* d_out, int out_size, void* d_ws, size_t ws_size,
                              hipStream_t stream){
    const float* pred = (const float*)d_in[0];
    const float* tgt  = (const float*)d_in[1];
    const float* lrr  = (const float*)d_in[2];
    float* out = (float*)d_out;

    double* part = (double*)d_ws;   // 2 * 3072 doubles = 48 KB, every slot written

    kmain<<<NIMG*8, 256, 0, stream>>>(pred, tgt, lrr, part);
    k3<<<1, 256, 0, stream>>>(part, out);
}

// Round 4
// 228.140 us; speedup vs baseline: 1.2669x; 1.2669x over previous
//
#include <hip/hip_runtime.h>

#define HW    512
#define OUTW  128
#define NIMG  96                          // 32*3
#define N_HR  ((long long)NIMG*HW*HW)     // 25165824
#define N_LR  ((long long)NIMG*OUTW*OUTW) // 1572864
#define NPART (NIMG*32)                   // one slot per wave (4 out rows each)

// PyTorch bicubic kernel, a = -0.75
__device__ __forceinline__ float cubic075(float x){
    float ax = fabsf(x);
    float ax2 = ax*ax, ax3 = ax2*ax;
    const float A = -0.75f;
    float f1 = (A+2.f)*ax3 - (A+3.f)*ax2 + 1.f;
    float f2 = A*ax3 - 5.f*A*ax2 + 8.f*A*ax - 4.f*A;
    return ax <= 1.f ? f1 : (ax < 2.f ? f2 : 0.f);
}

// scale=4 antialiased window: 16 taps, dist=(k-7.5)/4, normalized.
// Shift-invariant across all output positions (verified absmax=0.0).
__device__ __forceinline__ void get_weights(float w[16]){
    float s = 0.f;
#pragma unroll
    for (int k = 0; k < 16; ++k){
        float d = ((float)k - 7.5f) * 0.25f;
        w[k] = cubic075(d);
        s += w[k];
    }
#pragma unroll
    for (int k = 0; k < 16; ++k) w[k] /= s;
}

// async global->LDS DMA: 64 lanes x 16B = 1024B per call. LDS dest is
// wave-uniform base + lane*16 (HW-defined); global src is per-lane.
__device__ __forceinline__ void gl16(const float* g, float* l){
    __builtin_amdgcn_global_load_lds(
        (const __attribute__((address_space(1))) void*)g,
        (__attribute__((address_space(3))) void*)l,
        16, 0, 0);
}

// one 512-float row = 2 DMA instructions
__device__ __forceinline__ void stage_row(const float* rowbase, float* ldsbase, int l){
    gl16(rowbase + 4*l,       ldsbase);        // floats 0..255
    gl16(rowbase + 4*l + 256, ldsbase + 256);  // floats 256..511
}

// counted vmcnt wait; n is compile-time after full unroll -> folds to one asm.
// "memory" clobber fences the subsequent ds_reads (and keeps the tail lr
// loads from being hoisted into the counted window).
__device__ __forceinline__ void waitv(int n){
    if (n >= 8)      asm volatile("s_waitcnt vmcnt(8)" ::: "memory");
    else if (n == 6) asm volatile("s_waitcnt vmcnt(6)" ::: "memory");
    else if (n == 4) asm volatile("s_waitcnt vmcnt(4)" ::: "memory");
    else if (n == 2) asm volatile("s_waitcnt vmcnt(2)" ::: "memory");
    else             asm volatile("s_waitcnt vmcnt(0)" ::: "memory");
}

// R4: VGPR-resident pipelining failed 3 ways (R0 guarded->conservative
// drains; R1 unguarded->loads sunk, VGPR 36; R3 asm-pinned->rings spilled
// to scratch, VGPR 256, 92MB scratch writes). Switch to the HW path that
// needs no VGPRs for in-flight data: global_load_lds DMA into per-wave
// depth-3 LDS rings + hand-counted s_waitcnt vmcnt(N) (T3/T4 pattern,
// never draining to 0 in steady state). Fully unrolled so every ring
// index / guard / wait count is compile-time. Barrier-free (same-wave
// producer/consumer). LDS 48KB/block -> 3 blocks/CU (12 waves/CU, same
// as baseline); steady state keeps 8KB/wave = ~24MB chip-wide in flight.
__global__ __launch_bounds__(256) void kmain(const float* __restrict__ pred,
                                             const float* __restrict__ tgt,
                                             const float* __restrict__ lr,
                                             double* __restrict__ part){
    __shared__ float ringP[4][3][512];   // [wave][slot][col] 24 KB
    __shared__ float ringT[4][3][512];   // 24 KB

    const int img = blockIdx.x >> 3;
    const int tid = threadIdx.x;
    const int w   = tid >> 6;                 // wave in block 0..3
    const int l   = tid & 63;
    const int gw  = ((blockIdx.x & 7) << 2) + w;  // wave in image 0..31
    const int o0  = gw << 2;                  // first output row
    const int s   = (gw << 4) - 6;            // first (unclamped) input row

    float wt[16]; get_weights(wt);
    const float* P = pred + (size_t)img * (HW*HW);
    const float* T = tgt  + (size_t)img * (HW*HW);
    const float* L = lr   + (size_t)img * (OUTW*OUTW);

    float acc[4][2] = {{0.f,0.f},{0.f,0.f},{0.f,0.f},{0.f,0.f}};
    float pix_acc = 0.f, lr_acc = 0.f;

    // prime: rows 0,1 in flight (prefetch distance 2)
    {
        int r0 = min(HW-1, max(0, s + 0));
        int r1 = min(HW-1, max(0, s + 1));
        stage_row(P + (size_t)r0*HW, &ringP[w][0][0], l);
        stage_row(P + (size_t)r1*HW, &ringP[w][1][0], l);
    }

#pragma unroll
    for (int i = 0; i < 28; ++i){
        // issue prefetch group for row i+2 (pred, then tgt when in window)
        if (i + 2 < 28){
            int rr = min(HW-1, max(0, s + i + 2));
            stage_row(P + (size_t)rr*HW, &ringP[w][(i+2)%3][0], l);
        }
        if (i + 2 >= 6 && i + 2 < 22){
            stage_row(T + (size_t)(s+i+2)*HW, &ringT[w][(i+2)%3][0], l);
        }

        // wait for group i: allow the two younger groups (i+1, i+2) in flight
        const int Ni = ((i+1<28)?2:0) + ((i+1>=6 && i+1<22)?2:0)
                     + ((i+2<28)?2:0) + ((i+2>=6 && i+2<22)?2:0);
        waitv(Ni);

        // consume row i from LDS (ds_read_b128 x2 per stream)
        const float4* pr = (const float4*)(&ringP[w][i%3][0]);
        const float4 c0 = pr[2*l], c1 = pr[2*l+1];
        const float p0=c0.x,p1v=c0.y,p2v=c0.z,p3=c0.w,
                    p4=c1.x,p5=c1.y,p6=c1.z,p7=c1.w;

        // pix term: wave owns input rows s+6..s+21
        if (i >= 6 && i < 22){
            const float4* trp = (const float4*)(&ringT[w][i%3][0]);
            const float4 t0 = trp[2*l], t1 = trp[2*l+1];
            pix_acc += fabsf(p0-t0.x)+fabsf(p1v-t0.y)+fabsf(p2v-t0.z)+fabsf(p3-t0.w)
                     + fabsf(p4-t1.x)+fabsf(p5-t1.y)+fabsf(p6-t1.z)+fabsf(p7-t1.w);
        }

        // horizontal halo via shuffles: cols 8l-6..8l-1 and 8l+8..8l+13
        float Lm6 = __shfl_up(p2v,1,64), Lm5 = __shfl_up(p3,1,64),
              Lm4 = __shfl_up(p4,1,64),  Lm3 = __shfl_up(p5,1,64),
              Lm2 = __shfl_up(p6,1,64),  Lm1 = __shfl_up(p7,1,64);
        float R8  = __shfl_down(p0,1,64), R9  = __shfl_down(p1v,1,64),
              R10 = __shfl_down(p2v,1,64),R11 = __shfl_down(p3,1,64),
              R12 = __shfl_down(p4,1,64), R13 = __shfl_down(p5,1,64);
        if (l == 0){ Lm6=p0; Lm5=p0; Lm4=p0; Lm3=p0; Lm2=p0; Lm1=p0; }
        if (l == 63){ R8=p7; R9=p7; R10=p7; R11=p7; R12=p7; R13=p7; }

        float w20[20] = {Lm6,Lm5,Lm4,Lm3,Lm2,Lm1,p0,p1v,p2v,p3,p4,p5,p6,p7,
                         R8,R9,R10,R11,R12,R13};
        float h0 = 0.f, h1 = 0.f;
#pragma unroll
        for (int k = 0; k < 16; ++k){
            h0 += wt[k]*w20[k];
            h1 += wt[k]*w20[k+4];
        }

        // vertical accumulate into the 4 output rows this wave owns
#pragma unroll
        for (int q = 0; q < 4; ++q){
            int kk = i - 4*q;
            if (kk >= 0 && kk < 16){
                acc[q][0] += wt[kk]*h0;
                acc[q][1] += wt[kk]*h1;
            }
        }
    }

    // lr term: lane l holds out cols 2l,2l+1 for rows o0..o0+3
#pragma unroll
    for (int q = 0; q < 4; ++q){
        const float2 lv = *(const float2*)(L + (size_t)(o0+q)*OUTW + 2*l);
        lr_acc += fabsf(acc[q][0]-lv.x) + fabsf(acc[q][1]-lv.y);
    }

    // intra-wave reduction, one slot per wave (no atomics, no init needed)
#pragma unroll
    for (int off = 32; off > 0; off >>= 1){
        pix_acc += __shfl_down(pix_acc, off, 64);
        lr_acc  += __shfl_down(lr_acc,  off, 64);
    }
    if (l == 0){
        const int slot = (blockIdx.x << 2) + w;
        part[slot]         = (double)pix_acc;
        part[NPART + slot] = (double)lr_acc;
    }
}

__global__ __launch_bounds__(256) void k3(const double* __restrict__ part,
                                          float* __restrict__ out){
    const int t = threadIdx.x;
    double v1 = 0.0, v2 = 0.0;
    for (int i = t; i < NPART; i += 256){
        v1 += part[i];
        v2 += part[NPART + i];
    }
#pragma unroll
    for (int off = 32; off > 0; off >>= 1){
        v1 += __shfl_down(v1, off, 64);
        v2 += __shfl_down(v2, off, 64);
    }
    __shared__ double s1[4], s2[4];
    const int lane = t & 63, wid = t >> 6;
    if (lane == 0){ s1[wid] = v1; s2[wid] = v2; }
    __syncthreads();
    if (t == 0){
        double S1 = s1[0]+s1[1]+s1[2]+s1[3];
        double S2 = s2[0]+s2[1]+s2[2]+s2[3];
        float pix     = (float)(S1 / (double)N_HR);
        float lr_term = (float)(S2 / (double)N_LR);
        float pair    = 0.f;
        float consist = 1.0f * lr_term + 1.0f * pair;   // LAM_LR, LAM_PAIR
        float total   = pix + 0.1f * consist;           // LAM_CONSIST
        out[0] = total; out[1] = pix; out[2] = consist; out[3] = lr_term; out[4] = pair;
    }
}

extern "C" void kernel_launch(void* const* d_in, const int* in_sizes, int n_in,
                              void* d_out, int out_size, void* d_ws, size_t ws_size,
                              hipStream_t stream){
    const float* pred = (const float*)d_in[0];
    const float* tgt  = (const float*)d_in[1];
    const float* lrr  = (const float*)d_in[2];
    float* out = (float*)d_out;

    double* part = (double*)d_ws;   // 2 * 3072 doubles = 48 KB, every slot written

    kmain<<<NIMG*8, 256, 0, stream>>>(pred, tgt, lrr, part);
    k3<<<1, 256, 0, stream>>>(part, out);
}